// Round 11
// baseline (4606.330 us; speedup 1.0000x reference)
//
#include <hip/hip_runtime.h>
#include <math.h>

namespace {

constexpr int T_STEPS = 512;

typedef _Float16 h8v __attribute__((ext_vector_type(8)));
typedef _Float16 h4v __attribute__((ext_vector_type(4)));
typedef float    f4v __attribute__((ext_vector_type(4)));

__device__ __forceinline__ float sigf(float v) { return 1.0f / (1.0f + __expf(-v)); }
__device__ __forceinline__ float tanh_(float v) { return 2.0f / (1.0f + __expf(-2.0f * v)) - 1.0f; }

// Pack weights into MFMA B-fragment load order, fp16 (layout HW-verified R3+).
// Tile n (0..31) covers gates [16n,16n+16). Frag elem [l][j]: gate = 16n+(l&15),
// k = 32*ks + 8*(l>>4) + j.
// PA frag (n*6+ks): ks 0-1 = Wih0 (K=64), ks 2-5 = Whh0.
// PB frag (n*8+ks): ks 0-3 = Wih1, ks 4-7 = Whh1.
__global__ void pack_w(const float* __restrict__ Wih0, const float* __restrict__ Whh0,
                       const float* __restrict__ Wih1, const float* __restrict__ Whh1,
                       _Float16* __restrict__ PA, _Float16* __restrict__ PB) {
  int idx = blockIdx.x * 256 + threadIdx.x;
  if (idx < 98304) {
    int j = idx & 7, l = (idx >> 3) & 63;
    int f = idx >> 9;
    int ks = f % 6, n = f / 6;
    int gate = 16 * n + (l & 15);
    int k = 32 * ks + ((l >> 4) << 3) + j;
    float v = (k < 64) ? Wih0[gate * 64 + k] : Whh0[gate * 128 + (k - 64)];
    PA[idx] = (_Float16)v;
  } else if (idx < 229376) {
    int i = idx - 98304;
    int j = i & 7, l = (i >> 3) & 63;
    int f = i >> 9;
    int ks = f & 7, n = f >> 3;
    int gate = 16 * n + (l & 15);
    int k = 32 * ks + ((l >> 4) << 3) + j;
    float v = (k < 128) ? Wih1[gate * 128 + k] : Whh1[gate * 128 + (k - 128)];
    PB[i] = (_Float16)v;
  }
}

// 64 blocks x 1024 threads (16 waves, 4/SIMD). ROLE-SPLIT pipeline:
//   M0 = waves 0-3  : layer-0 gate MFMA -> zs0 (fp32, LDS)
//   M1 = waves 4-7  : layer-1 gate MFMA -> zs1
//   C  = waves 8-15 : ALL cell updates (trans-heavy), 4 cells/thread
// Wave->SIMD round-robin puts {M0, M1, C, C} on each SIMD, so every phase
// runs matrix-pipe work and trans-pipe work CONCURRENTLY (R10 post-mortem:
// homogeneous barrier-lockstep phases serialized through shared pipes).
// Schedule (2 barriers/step, lag pipeline — parity-audited):
//   phase1: M0: zs0(j)            | C: h1(j-2) = cells(zs1(j-2))
//   phase2: M1: zs1(j-1)          | C: h0(j)   = cells(zs0(j))  | M0: stage x(j+1)
// Buffers: h0t/h1t/xt double [j&1]; zs0/zs1 single (producer->barrier->consumer).
// Weights fully L2-streamed per step (448 KB/CU/step, LICM-defeated; all 64
// blocks read the same lines -> L2-hot). No AGPR needed: M-waves hold no cell
// state, C-waves hold no weights -> everyone fits 128 regs at 4 waves/SIMD.
__global__ __launch_bounds__(1024) void lstm_pipe2(
    const float* __restrict__ x,
    const _Float16* __restrict__ PA, const _Float16* __restrict__ PB,
    const float* __restrict__ b0, const float* __restrict__ b1,
    const float* __restrict__ Wout, const float* __restrict__ bout,
    float* __restrict__ out) {
  extern __shared__ char smem[];
  f4v* zs0 = (f4v*)smem;             // [32 n][64 l] f32x4 = 32 KB
  f4v* zs1 = (f4v*)(smem + 32768);   // 32 KB
  _Float16(*h0t)[4][64][8] = (_Float16(*)[4][64][8])(smem + 65536);  // [2][4][64][8] 8 KB
  _Float16(*h1t)[4][64][8] = (_Float16(*)[4][64][8])(smem + 73728);  // 8 KB
  _Float16(*xt)[2][64][8]  = (_Float16(*)[2][64][8])(smem + 81920);  // [2][2][64][8] 4 KB

  const int tid = threadIdx.x;
  const int g = blockIdx.x;
  const int wv = tid >> 6, l = tid & 63;
  const int lo = l & 15, hi = l >> 4;

  const h8v* PAv = (const h8v*)PA;
  const h8v* PBv = (const h8v*)PB;

  // role-local state
  float br[8] = {0, 0, 0, 0, 0, 0, 0, 0};       // M-wave biases
  float c0[4] = {0.f, 0.f, 0.f, 0.f};           // C-wave cell states
  float c1[4] = {0.f, 0.f, 0.f, 0.f};
  if (wv < 4) {
    int w = wv;
#pragma unroll
    for (int t = 0; t < 4; ++t)
#pragma unroll
      for (int s = 0; s < 2; ++s) br[2 * t + s] = b0[128 * t + 32 * w + 16 * s + lo];
  } else if (wv < 8) {
    int w = wv - 4;
#pragma unroll
    for (int t = 0; t < 4; ++t)
#pragma unroll
      for (int s = 0; s < 2; ++s) br[2 * t + s] = b1[128 * t + 32 * w + 16 * s + lo];
  }

  // zero h tiles (both parities), stage x(0) -> xt[0]
  {
    unsigned int* z0 = (unsigned int*)h0t;
    unsigned int* z1 = (unsigned int*)h1t;
    for (int i = tid; i < 2048; i += 1024) { z0[i] = 0u; z1[i] = 0u; }
    if (tid < 256) {
      int row = tid >> 4, kk = (tid & 15) << 2;
      float4 v = *(const float4*)(x + (((long)(g * 16 + row)) * T_STEPS) * 64 + kk);
      h4v pv;
      pv.x = (_Float16)v.x; pv.y = (_Float16)v.y;
      pv.z = (_Float16)v.z; pv.w = (_Float16)v.w;
      *(h4v*)&xt[0][kk >> 5][(((kk >> 3) & 3) * 16) + row][kk & 7] = pv;
    }
  }
  __syncthreads();

  for (int j = 0; j <= T_STEPS + 1; ++j) {
    const int p = j & 1;

    // ================= phase 1 : M0 zs0(j)  ||  C h1(j-2) =================
    if (wv < 4) {
      if (j < T_STEPS) {
        int w = wv;
        int zoff = 0;
        asm volatile("" : "+v"(zoff));  // defeat LICM on streamed weights
        h8v ax0 = *(const h8v*)&xt[p][0][l][0];
        h8v ax1 = *(const h8v*)&xt[p][1][l][0];
        h8v h00 = *(const h8v*)&h0t[p ^ 1][0][l][0];
        h8v h01 = *(const h8v*)&h0t[p ^ 1][1][l][0];
        h8v h02 = *(const h8v*)&h0t[p ^ 1][2][l][0];
        h8v h03 = *(const h8v*)&h0t[p ^ 1][3][l][0];
#pragma unroll
        for (int s = 0; s < 2; ++s)
#pragma unroll
          for (int t = 0; t < 4; ++t) {
            int q = 2 * t + s, n = 8 * t + 2 * w + s;
            const h8v* wp = PAv + (long)(n * 6) * 64 + l + zoff;
            h8v w0 = wp[0], w1 = wp[64], w2 = wp[128];
            h8v w3 = wp[192], w4 = wp[256], w5 = wp[320];
            f4v z = {br[q], br[q], br[q], br[q]};
            z = __builtin_amdgcn_mfma_f32_16x16x32_f16(ax0, w0, z, 0, 0, 0);
            z = __builtin_amdgcn_mfma_f32_16x16x32_f16(ax1, w1, z, 0, 0, 0);
            z = __builtin_amdgcn_mfma_f32_16x16x32_f16(h00, w2, z, 0, 0, 0);
            z = __builtin_amdgcn_mfma_f32_16x16x32_f16(h01, w3, z, 0, 0, 0);
            z = __builtin_amdgcn_mfma_f32_16x16x32_f16(h02, w4, z, 0, 0, 0);
            z = __builtin_amdgcn_mfma_f32_16x16x32_f16(h03, w5, z, 0, 0, 0);
            zs0[n * 64 + l] = z;
          }
      }
    } else if (wv >= 8) {
      if (j >= 2) {  // h1(j-2) from zs1(j-2); write h1t[(j-2)&1] = h1t[p]
        int cw = wv - 8;
        f4v r0 = zs1[(cw) * 64 + l];
        f4v r1 = zs1[(8 + cw) * 64 + l];
        f4v r2 = zs1[(16 + cw) * 64 + l];
        f4v r3 = zs1[(24 + cw) * 64 + l];
#pragma unroll
        for (int r = 0; r < 4; ++r) {
          float cn = sigf(r1[r]) * c1[r] + sigf(r0[r]) * tanh_(r2[r]);
          c1[r] = cn;
          float hv = sigf(r3[r]) * tanh_(cn);
          h1t[p][cw >> 1][(2 * (cw & 1) + (lo >> 3)) * 16 + hi * 4 + r][lo & 7] = (_Float16)hv;
        }
      }
    }
    __syncthreads();

    // ============ phase 2 : M1 zs1(j-1) || C h0(j) || M0 stage x ============
    if (wv < 4) {
      if (j < T_STEPS - 1) {  // stage x(j+1) -> xt[p^1] (M0 idle otherwise)
        int row = tid >> 4, kk = (tid & 15) << 2;
        float4 v = *(const float4*)(x + (((long)(g * 16 + row)) * T_STEPS + (j + 1)) * 64 + kk);
        h4v pv;
        pv.x = (_Float16)v.x; pv.y = (_Float16)v.y;
        pv.z = (_Float16)v.z; pv.w = (_Float16)v.w;
        *(h4v*)&xt[p ^ 1][kk >> 5][(((kk >> 3) & 3) * 16) + row][kk & 7] = pv;
      }
    } else if (wv < 8) {
      if (j >= 1 && j <= T_STEPS) {  // zs1(j-1): h0(j-1)=h0t[p^1], h1(j-2)=h1t[p]
        int w = wv - 4;
        int zoff = 0;
        asm volatile("" : "+v"(zoff));
        h8v h00 = *(const h8v*)&h0t[p ^ 1][0][l][0];
        h8v h01 = *(const h8v*)&h0t[p ^ 1][1][l][0];
        h8v h02 = *(const h8v*)&h0t[p ^ 1][2][l][0];
        h8v h03 = *(const h8v*)&h0t[p ^ 1][3][l][0];
        h8v f10 = *(const h8v*)&h1t[p][0][l][0];
        h8v f11 = *(const h8v*)&h1t[p][1][l][0];
        h8v f12 = *(const h8v*)&h1t[p][2][l][0];
        h8v f13 = *(const h8v*)&h1t[p][3][l][0];
#pragma unroll
        for (int s = 0; s < 2; ++s)
#pragma unroll
          for (int t = 0; t < 4; ++t) {
            int q = 2 * t + s, n = 8 * t + 2 * w + s;
            const h8v* wp = PBv + (long)(n * 8) * 64 + l + zoff;
            h8v w0 = wp[0], w1 = wp[64], w2 = wp[128], w3 = wp[192];
            h8v w4 = wp[256], w5 = wp[320], w6 = wp[384], w7 = wp[448];
            f4v z = {br[q], br[q], br[q], br[q]};
            z = __builtin_amdgcn_mfma_f32_16x16x32_f16(h00, w0, z, 0, 0, 0);
            z = __builtin_amdgcn_mfma_f32_16x16x32_f16(h01, w1, z, 0, 0, 0);
            z = __builtin_amdgcn_mfma_f32_16x16x32_f16(h02, w2, z, 0, 0, 0);
            z = __builtin_amdgcn_mfma_f32_16x16x32_f16(h03, w3, z, 0, 0, 0);
            z = __builtin_amdgcn_mfma_f32_16x16x32_f16(f10, w4, z, 0, 0, 0);
            z = __builtin_amdgcn_mfma_f32_16x16x32_f16(f11, w5, z, 0, 0, 0);
            z = __builtin_amdgcn_mfma_f32_16x16x32_f16(f12, w6, z, 0, 0, 0);
            z = __builtin_amdgcn_mfma_f32_16x16x32_f16(f13, w7, z, 0, 0, 0);
            zs1[n * 64 + l] = z;
          }
      }
    } else {
      if (j < T_STEPS) {  // h0(j) from zs0(j); write h0t[j&1] = h0t[p]
        int cw = wv - 8;
        f4v r0 = zs0[(cw) * 64 + l];
        f4v r1 = zs0[(8 + cw) * 64 + l];
        f4v r2 = zs0[(16 + cw) * 64 + l];
        f4v r3 = zs0[(24 + cw) * 64 + l];
#pragma unroll
        for (int r = 0; r < 4; ++r) {
          float cn = sigf(r1[r]) * c0[r] + sigf(r0[r]) * tanh_(r2[r]);
          c0[r] = cn;
          float hv = sigf(r3[r]) * tanh_(cn);
          h0t[p][cw >> 1][(2 * (cw & 1) + (lo >> 3)) * 16 + hi * 4 + r][lo & 7] = (_Float16)hv;
        }
      }
    }
    __syncthreads();
  }

  // ---- output projection: y = h1(T-1) . Wout^T + bout ; h1(T-1) in h1t[1] ----
  if (tid < 16) {
    float acc = bout[0];
#pragma unroll 4
    for (int u = 0; u < 128; ++u) {
      float hval = (float)h1t[1][u >> 5][(((u >> 3) & 3) * 16) + tid][u & 7];
      acc = fmaf(hval, Wout[u], acc);
    }
    out[g * 16 + tid] = acc;
  }
}

}  // namespace

extern "C" void kernel_launch(void* const* d_in, const int* in_sizes, int n_in,
                              void* d_out, int out_size, void* d_ws, size_t ws_size,
                              hipStream_t stream) {
  const float* x    = (const float*)d_in[0];
  const float* Wih0 = (const float*)d_in[1];
  const float* Whh0 = (const float*)d_in[2];
  const float* b0   = (const float*)d_in[3];
  const float* Wih1 = (const float*)d_in[4];
  const float* Whh1 = (const float*)d_in[5];
  const float* b1   = (const float*)d_in[6];
  const float* Wout = (const float*)d_in[7];
  const float* bout = (const float*)d_in[8];
  float* out = (float*)d_out;

  char* ws = (char*)d_ws;
  _Float16* PA = (_Float16*)ws;             // 196608 B
  _Float16* PB = (_Float16*)(ws + 196608);  // 262144 B

  const int lds_bytes = 32768 + 32768 + 8192 + 8192 + 4096;  // 86016
  hipFuncSetAttribute((const void*)lstm_pipe2,
                      hipFuncAttributeMaxDynamicSharedMemorySize, lds_bytes);

  pack_w<<<dim3(896), dim3(256), 0, stream>>>(Wih0, Whh0, Wih1, Whh1, PA, PB);
  lstm_pipe2<<<dim3(64), dim3(1024), lds_bytes, stream>>>(
      x, PA, PB, b0, b1, Wout, bout, out);
}

// Round 12
// 1872.605 us; speedup vs baseline: 2.4599x; 2.4599x over previous
//
#include <hip/hip_runtime.h>
#include <math.h>

namespace {

constexpr int T_STEPS = 512;

typedef _Float16 h8v __attribute__((ext_vector_type(8)));
typedef _Float16 h2v __attribute__((ext_vector_type(2)));
typedef float    f4v __attribute__((ext_vector_type(4)));
typedef int      i4v __attribute__((ext_vector_type(4)));

__device__ __forceinline__ float sigf(float v) { return 1.0f / (1.0f + __expf(-v)); }
__device__ __forceinline__ float tanh_(float v) { return 2.0f / (1.0f + __expf(-2.0f * v)) - 1.0f; }

// Pack weights into MFMA B-fragment load order, fp16 (layout HW-verified R3-R6).
// PA (layer0): frag f = (w*4+q)*6 + ks, elem [l][j]:
//   gate = 16*(8q+w) + (l&15), k = 32*ks + 8*(l>>4) + j ; ks 0-1 Wih0, ks 2-5 Whh0.
// PB (layer1): 8 ks: 0-3 Wih1, 4-7 Whh1.
__global__ void pack_w(const float* __restrict__ Wih0, const float* __restrict__ Whh0,
                       const float* __restrict__ Wih1, const float* __restrict__ Whh1,
                       _Float16* __restrict__ PA, _Float16* __restrict__ PB) {
  int idx = blockIdx.x * 256 + threadIdx.x;
  if (idx < 98304) {
    int j = idx & 7, l = (idx >> 3) & 63;
    int f = idx >> 9;
    int ks = f % 6, wq = f / 6;
    int q = wq & 3, w = wq >> 2;
    int gate = 16 * (8 * q + w) + (l & 15);
    int k = 32 * ks + ((l >> 4) << 3) + j;
    float v = (k < 64) ? Wih0[gate * 64 + k] : Whh0[gate * 128 + (k - 64)];
    PA[idx] = (_Float16)v;
  } else if (idx < 98304 + 131072) {
    int i = idx - 98304;
    int j = i & 7, l = (i >> 3) & 63;
    int f = i >> 9;
    int ks = f & 7, wq = f >> 3;
    int q = wq & 3, w = wq >> 2;
    int gate = 16 * (8 * q + w) + (l & 15);
    int k = 32 * ks + ((l >> 4) << 3) + j;
    float v = (k < 128) ? Wih1[gate * 128 + k] : Whh1[gate * 128 + (k - 128)];
    PB[i] = (_Float16)v;
  }
}

// R6 structure (best: 1687us) + AGPR weight residency (R10-proven no-spill
// config: 128 VGPR + 128 AGPR at 2 waves/SIMD). 64 blocks x 512 threads
// (8 waves, 2/SIMD). Fused pipeline: iter j = layer0 step j + layer1 step j-1
// (independent), ONE barrier/iter; wave w owns units [16w,16w+16) x 4 gates
// for both layers. Weights:
//   AGPR ("+a", 128 regs): W0 (Wih0+Whh0, 24 frags) + Wih1 q0,1 (8 frags)
//   LDS: Whh1 (128 KB) + h/x tiles (20 KB)
//   L2 stream (32 KB/step, LICM-defeated): Wih1 q2,3
// c state fp32 in registers; cell update lane-local.
__global__ __attribute__((amdgpu_waves_per_eu(2, 2))) __launch_bounds__(512)
void lstm_block(
    const float* __restrict__ x,
    const _Float16* __restrict__ PA, const _Float16* __restrict__ PB,
    const float* __restrict__ b0, const float* __restrict__ b1,
    const float* __restrict__ Wout, const float* __restrict__ bout,
    float* __restrict__ out) {
  extern __shared__ char smem[];
  h8v* whh = (h8v*)smem;  // Whh1 B-frags: [32 wq][4 ks4][64 l] = 128 KB
  _Float16(*h0t)[4][64][8] = (_Float16(*)[4][64][8])(smem + 131072);          // [2][4][64][8] 8 KB
  _Float16(*h1t)[4][64][8] = (_Float16(*)[4][64][8])(smem + 131072 + 8192);   // 8 KB
  _Float16(*xt)[2][64][8]  = (_Float16(*)[2][64][8])(smem + 131072 + 16384);  // [2][2][64][8] 4 KB

  const int tid = threadIdx.x;
  const int g = blockIdx.x;
  const int w = tid >> 6, l = tid & 63;
  const int lo = l & 15, hi = l >> 4;
  const int unit = 16 * w + lo;
  const int kb_w = w >> 1;
  const int sub_w = (2 * w + (lo >> 3)) & 3;
  const int lanep = sub_w * 16 + hi * 4;  // + r
  const int jw = lo & 7;

  const i4v* PAi = (const i4v*)PA;
  const i4v* PBi = (const i4v*)PB;

  // ---- AGPR-resident weights: 32 frags = 128 AGPRs ("+a" pinned) ----
  i4v W0a[4][6];   // layer-0: all 24 frags
  i4v W1a[2][4];   // layer-1 Wih1, q = 0,1 only (8 frags)
#pragma unroll
  for (int q = 0; q < 4; ++q)
#pragma unroll
    for (int ks = 0; ks < 6; ++ks) W0a[q][ks] = PAi[((w * 4 + q) * 6 + ks) * 64 + l];
#pragma unroll
  for (int q = 0; q < 2; ++q)
#pragma unroll
    for (int ks = 0; ks < 4; ++ks) W1a[q][ks] = PBi[((w * 4 + q) * 8 + ks) * 64 + l];
#pragma unroll
  for (int q = 0; q < 4; ++q)
#pragma unroll
    for (int ks = 0; ks < 6; ++ks) asm volatile("" : "+a"(W0a[q][ks]));
#pragma unroll
  for (int q = 0; q < 2; ++q)
#pragma unroll
    for (int ks = 0; ks < 4; ++ks) asm volatile("" : "+a"(W1a[q][ks]));

  float bA[4], bB[4];
#pragma unroll
  for (int q = 0; q < 4; ++q) { bA[q] = b0[unit + 128 * q]; bB[q] = b1[unit + 128 * q]; }
  float c0[4] = {0.f, 0.f, 0.f, 0.f}, c1[4] = {0.f, 0.f, 0.f, 0.f};

  // ---- stage Whh1 fragments into LDS ----
  for (int i = tid; i < 8192; i += 512) {
    int l2 = i & 63, f = i >> 6;
    int ks4 = f & 3, wq = f >> 2;
    ((i4v*)whh)[i] = PBi[(wq * 8 + 4 + ks4) * 64 + l2];
  }
  // ---- zero h0t/h1t, stage x(0) ----
  {
    unsigned int* z0 = (unsigned int*)h0t;
    unsigned int* z1 = (unsigned int*)h1t;
    for (int i = tid; i < 2048; i += 512) { z0[i] = 0u; z1[i] = 0u; }
    int row = tid >> 5, kk = (tid & 31) << 1;
    const float* xp = x + (((long)(g * 16 + row)) * T_STEPS + 0) * 64 + kk;
    float2 v = *(const float2*)xp;
    h2v pxv; pxv.x = (_Float16)v.x; pxv.y = (_Float16)v.y;
    *(h2v*)&xt[0][kk >> 5][(((kk >> 3) & 3) * 16) + row][kk & 7] = pxv;
  }
  __syncthreads();

  // Fused: iter j = A(j) [layer0 step j] + B(j-1) [layer1 step j-1].
  for (int j = 0; j <= T_STEPS; ++j) {
    const int p = j & 1;

    // shared h0(j-1) fragments (A-operand for BOTH layers)
    h8v h00 = *(const h8v*)&h0t[p][0][l][0];
    h8v h01 = *(const h8v*)&h0t[p][1][l][0];
    h8v h02 = *(const h8v*)&h0t[p][2][l][0];
    h8v h03 = *(const h8v*)&h0t[p][3][l][0];

    if (j < T_STEPS) {
      // ---- A(j): layer 0 computes h0(j) ----
      h8v ax0 = *(const h8v*)&xt[p][0][l][0];
      h8v ax1 = *(const h8v*)&xt[p][1][l][0];
      f4v accA[4];
#pragma unroll
      for (int q = 0; q < 4; ++q) {
        f4v z = {bA[q], bA[q], bA[q], bA[q]};
        z = __builtin_amdgcn_mfma_f32_16x16x32_f16(ax0, __builtin_bit_cast(h8v, W0a[q][0]), z, 0, 0, 0);
        z = __builtin_amdgcn_mfma_f32_16x16x32_f16(ax1, __builtin_bit_cast(h8v, W0a[q][1]), z, 0, 0, 0);
        z = __builtin_amdgcn_mfma_f32_16x16x32_f16(h00, __builtin_bit_cast(h8v, W0a[q][2]), z, 0, 0, 0);
        z = __builtin_amdgcn_mfma_f32_16x16x32_f16(h01, __builtin_bit_cast(h8v, W0a[q][3]), z, 0, 0, 0);
        z = __builtin_amdgcn_mfma_f32_16x16x32_f16(h02, __builtin_bit_cast(h8v, W0a[q][4]), z, 0, 0, 0);
        z = __builtin_amdgcn_mfma_f32_16x16x32_f16(h03, __builtin_bit_cast(h8v, W0a[q][5]), z, 0, 0, 0);
        accA[q] = z;
      }
#pragma unroll
      for (int r = 0; r < 4; ++r) {
        float cn = sigf(accA[1][r]) * c0[r] + sigf(accA[0][r]) * tanh_(accA[2][r]);
        c0[r] = cn;
        float hv = sigf(accA[3][r]) * tanh_(cn);
        h0t[p ^ 1][kb_w][lanep + r][jw] = (_Float16)hv;
      }
      if (j + 1 < T_STEPS) {  // stage x(j+1)
        int row = tid >> 5, kk = (tid & 31) << 1;
        const float* xp = x + (((long)(g * 16 + row)) * T_STEPS + (j + 1)) * 64 + kk;
        float2 v = *(const float2*)xp;
        h2v pxv; pxv.x = (_Float16)v.x; pxv.y = (_Float16)v.y;
        *(h2v*)&xt[p ^ 1][kk >> 5][(((kk >> 3) & 3) * 16) + row][kk & 7] = pxv;
      }
    }

    if (j >= 1) {
      // ---- B(j-1): layer 1 computes h1(j-1) ----
      int zoff = 0;
      asm volatile("" : "+v"(zoff));  // keep q2,3 Wih1 loads IN-loop (no hoist-and-pin)
      h8v f10 = *(const h8v*)&h1t[p][0][l][0];
      h8v f11 = *(const h8v*)&h1t[p][1][l][0];
      h8v f12 = *(const h8v*)&h1t[p][2][l][0];
      h8v f13 = *(const h8v*)&h1t[p][3][l][0];
      // streamed Wih1 q=2,3 (issue early, use late; 32 KB/step, L2-hot)
      h8v gw[2][4];
#pragma unroll
      for (int qq = 0; qq < 2; ++qq)
#pragma unroll
        for (int ks = 0; ks < 4; ++ks)
          gw[qq][ks] = __builtin_bit_cast(h8v, PBi[((w * 4 + 2 + qq) * 8 + ks) * 64 + l + zoff]);
      f4v accB[4];
#pragma unroll
      for (int q = 0; q < 4; ++q) {
        const h8v* wb = &whh[((w * 4 + q) * 4) * 64 + l];
        h8v wh0 = wb[0];
        h8v wh1 = wb[64];
        h8v wh2 = wb[128];
        h8v wh3 = wb[192];
        h8v wi0 = (q < 2) ? __builtin_bit_cast(h8v, W1a[q & 1][0]) : gw[q & 1][0];
        h8v wi1 = (q < 2) ? __builtin_bit_cast(h8v, W1a[q & 1][1]) : gw[q & 1][1];
        h8v wi2 = (q < 2) ? __builtin_bit_cast(h8v, W1a[q & 1][2]) : gw[q & 1][2];
        h8v wi3 = (q < 2) ? __builtin_bit_cast(h8v, W1a[q & 1][3]) : gw[q & 1][3];
        f4v z = {bB[q], bB[q], bB[q], bB[q]};
        z = __builtin_amdgcn_mfma_f32_16x16x32_f16(h00, wi0, z, 0, 0, 0);
        z = __builtin_amdgcn_mfma_f32_16x16x32_f16(h01, wi1, z, 0, 0, 0);
        z = __builtin_amdgcn_mfma_f32_16x16x32_f16(h02, wi2, z, 0, 0, 0);
        z = __builtin_amdgcn_mfma_f32_16x16x32_f16(h03, wi3, z, 0, 0, 0);
        z = __builtin_amdgcn_mfma_f32_16x16x32_f16(f10, wh0, z, 0, 0, 0);
        z = __builtin_amdgcn_mfma_f32_16x16x32_f16(f11, wh1, z, 0, 0, 0);
        z = __builtin_amdgcn_mfma_f32_16x16x32_f16(f12, wh2, z, 0, 0, 0);
        z = __builtin_amdgcn_mfma_f32_16x16x32_f16(f13, wh3, z, 0, 0, 0);
        accB[q] = z;
      }
#pragma unroll
      for (int r = 0; r < 4; ++r) {
        float cn = sigf(accB[1][r]) * c1[r] + sigf(accB[0][r]) * tanh_(accB[2][r]);
        c1[r] = cn;
        float hv = sigf(accB[3][r]) * tanh_(cn);
        h1t[p ^ 1][kb_w][lanep + r][jw] = (_Float16)hv;
      }
    }
    __syncthreads();
  }

  // ---- output projection: y = h1(T-1) . Wout^T + bout ; h1(T-1) in h1t[1] ----
  if (tid < 16) {
    float acc = bout[0];
#pragma unroll 4
    for (int u = 0; u < 128; ++u) {
      float hval = (float)h1t[1][u >> 5][(((u >> 3) & 3) * 16) + tid][u & 7];
      acc = fmaf(hval, Wout[u], acc);
    }
    out[g * 16 + tid] = acc;
  }
}

}  // namespace

extern "C" void kernel_launch(void* const* d_in, const int* in_sizes, int n_in,
                              void* d_out, int out_size, void* d_ws, size_t ws_size,
                              hipStream_t stream) {
  const float* x    = (const float*)d_in[0];
  const float* Wih0 = (const float*)d_in[1];
  const float* Whh0 = (const float*)d_in[2];
  const float* b0   = (const float*)d_in[3];
  const float* Wih1 = (const float*)d_in[4];
  const float* Whh1 = (const float*)d_in[5];
  const float* b1   = (const float*)d_in[6];
  const float* Wout = (const float*)d_in[7];
  const float* bout = (const float*)d_in[8];
  float* out = (float*)d_out;

  char* ws = (char*)d_ws;
  _Float16* PA = (_Float16*)ws;             // 196608 B
  _Float16* PB = (_Float16*)(ws + 196608);  // 262144 B

  const int lds_bytes = 131072 + 8192 + 8192 + 4096;  // 151552
  hipFuncSetAttribute((const void*)lstm_block,
                      hipFuncAttributeMaxDynamicSharedMemorySize, lds_bytes);

  pack_w<<<dim3(896), dim3(256), 0, stream>>>(Wih0, Whh0, Wih1, Whh1, PA, PB);
  lstm_block<<<dim3(64), dim3(512), lds_bytes, stream>>>(
      x, PA, PB, b0, b1, Wout, bout, out);
}

// Round 13
// 1290.752 us; speedup vs baseline: 3.5687x; 1.4508x over previous
//
#include <hip/hip_runtime.h>
#include <math.h>

namespace {

constexpr int T_STEPS = 512;

typedef _Float16 h8v __attribute__((ext_vector_type(8)));
typedef _Float16 h2v __attribute__((ext_vector_type(2)));
typedef float    f4v __attribute__((ext_vector_type(4)));

// Fast gate activations: IEEE divide (v_div_scale/fmas/fixup ~8-10 VALU insts)
// was ~half the kernel's VALU issue (R12 post-mortem: 74% VALUBusy on active
// CUs, ~1460 insts/wave/step vs ~300 intended). v_rcp_f32 is 1 inst, ~1e-7
// rel err -- negligible vs the 2.4e-4 fp16 error budget.
__device__ __forceinline__ float sigf(float v) {
  return __builtin_amdgcn_rcpf(1.0f + __builtin_amdgcn_exp2f(-1.442695041f * v));
}
__device__ __forceinline__ float tanh_(float v) {
  return 2.0f * __builtin_amdgcn_rcpf(1.0f + __builtin_amdgcn_exp2f(-2.885390082f * v)) - 1.0f;
}

// Pack weights into MFMA B-fragment load order, fp16 (verified on HW R3-R12).
// PA (layer0): frag f = (w*4+q)*6 + ks, elem [l][j]:
//   gate = 16*(8q+w) + (l&15), k = 32*ks + 8*(l>>4) + j ; ks 0-1 Wih0, ks 2-5 Whh0.
// PB (layer1): 8 ks: 0-3 Wih1, 4-7 Whh1.
__global__ void pack_w(const float* __restrict__ Wih0, const float* __restrict__ Whh0,
                       const float* __restrict__ Wih1, const float* __restrict__ Whh1,
                       _Float16* __restrict__ PA, _Float16* __restrict__ PB) {
  int idx = blockIdx.x * 256 + threadIdx.x;
  if (idx < 98304) {
    int j = idx & 7, l = (idx >> 3) & 63;
    int f = idx >> 9;
    int ks = f % 6, wq = f / 6;
    int q = wq & 3, w = wq >> 2;
    int gate = 16 * (8 * q + w) + (l & 15);
    int k = 32 * ks + ((l >> 4) << 3) + j;
    float v = (k < 64) ? Wih0[gate * 64 + k] : Whh0[gate * 128 + (k - 64)];
    PA[idx] = (_Float16)v;
  } else if (idx < 98304 + 131072) {
    int i = idx - 98304;
    int j = i & 7, l = (i >> 3) & 63;
    int f = i >> 9;
    int ks = f & 7, wq = f >> 3;
    int q = wq & 3, w = wq >> 2;
    int gate = 16 * (8 * q + w) + (l & 15);
    int k = 32 * ks + ((l >> 4) << 3) + j;
    float v = (k < 128) ? Wih1[gate * 128 + k] : Whh1[gate * 128 + (k - 128)];
    PB[i] = (_Float16)v;
  }
}

// R6 structure verbatim (best: 1687us) with ONLY the activation functions
// changed to rcp-based (single-variable A/B). 64 blocks x 512 threads
// (8 waves, 2/SIMD), 1 block/CU. Fused pipeline: iter j = layer0 step j +
// layer1 step j-1 (independent), ONE barrier/iter; wave w owns units
// [16w,16w+16) x 4 gate types for both layers; lane-local cell update,
// c fp32 in registers. Weights: W0+Wih1 nominal-register (compiler remats
// from L2 at VGPR=128 -- measured acceptable), Whh1 in LDS (128 KB).
__global__ __attribute__((amdgpu_waves_per_eu(2, 2))) __launch_bounds__(512)
void lstm_block(
    const float* __restrict__ x,
    const _Float16* __restrict__ PA, const _Float16* __restrict__ PB,
    const float* __restrict__ b0, const float* __restrict__ b1,
    const float* __restrict__ Wout, const float* __restrict__ bout,
    float* __restrict__ out) {
  extern __shared__ char smem[];
  h8v* whh = (h8v*)smem;  // Whh1 B-frags: [32 wq][4 ks4][64 l] = 128 KB
  _Float16(*h0t)[4][64][8] = (_Float16(*)[4][64][8])(smem + 131072);          // [2][4][64][8] 8 KB
  _Float16(*h1t)[4][64][8] = (_Float16(*)[4][64][8])(smem + 131072 + 8192);   // 8 KB
  _Float16(*xt)[2][64][8]  = (_Float16(*)[2][64][8])(smem + 131072 + 16384);  // [2][2][64][8] 4 KB

  const int tid = threadIdx.x;
  const int g = blockIdx.x;
  const int w = tid >> 6, l = tid & 63;
  const int lo = l & 15, hi = l >> 4;
  const int unit = 16 * w + lo;
  const int kb_w = w >> 1;
  const int sub_w = (2 * w + (lo >> 3)) & 3;
  const int lanep = sub_w * 16 + hi * 4;  // + r
  const int jw = lo & 7;

  // ---- persistent register weights ----
  const h8v* PAv = (const h8v*)PA;
  const h8v* PBv = (const h8v*)PB;
  h8v W0[4][6], W1[4][4];
#pragma unroll
  for (int q = 0; q < 4; ++q) {
#pragma unroll
    for (int ks = 0; ks < 6; ++ks) W0[q][ks] = PAv[((w * 4 + q) * 6 + ks) * 64 + l];
#pragma unroll
    for (int ks = 0; ks < 4; ++ks) W1[q][ks] = PBv[((w * 4 + q) * 8 + ks) * 64 + l];
  }
#pragma unroll
  for (int q = 0; q < 4; ++q) {
#pragma unroll
    for (int ks = 0; ks < 6; ++ks) asm volatile("" : "+v"(W0[q][ks]));
#pragma unroll
    for (int ks = 0; ks < 4; ++ks) asm volatile("" : "+v"(W1[q][ks]));
  }
  float bA[4], bB[4];
#pragma unroll
  for (int q = 0; q < 4; ++q) { bA[q] = b0[unit + 128 * q]; bB[q] = b1[unit + 128 * q]; }
  float c0[4] = {0.f, 0.f, 0.f, 0.f}, c1[4] = {0.f, 0.f, 0.f, 0.f};

  // ---- stage Whh1 fragments into LDS ----
  for (int i = tid; i < 8192; i += 512) {
    int l2 = i & 63, f = i >> 6;
    int ks4 = f & 3, wq = f >> 2;
    whh[i] = PBv[(wq * 8 + 4 + ks4) * 64 + l2];
  }
  // ---- zero h0t/h1t, stage x(0) ----
  {
    unsigned int* z0 = (unsigned int*)h0t;
    unsigned int* z1 = (unsigned int*)h1t;
    for (int i = tid; i < 2048; i += 512) { z0[i] = 0u; z1[i] = 0u; }
    int row = tid >> 5, kk = (tid & 31) << 1;
    const float* xp = x + (((long)(g * 16 + row)) * T_STEPS + 0) * 64 + kk;
    float2 v = *(const float2*)xp;
    h2v pxv; pxv.x = (_Float16)v.x; pxv.y = (_Float16)v.y;
    *(h2v*)&xt[0][kk >> 5][(((kk >> 3) & 3) * 16) + row][kk & 7] = pxv;
  }
  __syncthreads();

  // Fused: iter j = A(j) [layer0 step j] + B(j-1) [layer1 step j-1].
  for (int j = 0; j <= T_STEPS; ++j) {
    const int p = j & 1;

    // shared h0(j-1) fragments (A-operand for BOTH layers)
    h8v h00 = *(const h8v*)&h0t[p][0][l][0];
    h8v h01 = *(const h8v*)&h0t[p][1][l][0];
    h8v h02 = *(const h8v*)&h0t[p][2][l][0];
    h8v h03 = *(const h8v*)&h0t[p][3][l][0];

    if (j < T_STEPS) {
      // ---- A(j): layer 0 computes h0(j) ----
      h8v ax0 = *(const h8v*)&xt[p][0][l][0];
      h8v ax1 = *(const h8v*)&xt[p][1][l][0];
      f4v accA[4];
#pragma unroll
      for (int q = 0; q < 4; ++q) {
        f4v z = {bA[q], bA[q], bA[q], bA[q]};
        z = __builtin_amdgcn_mfma_f32_16x16x32_f16(ax0, W0[q][0], z, 0, 0, 0);
        z = __builtin_amdgcn_mfma_f32_16x16x32_f16(ax1, W0[q][1], z, 0, 0, 0);
        z = __builtin_amdgcn_mfma_f32_16x16x32_f16(h00, W0[q][2], z, 0, 0, 0);
        z = __builtin_amdgcn_mfma_f32_16x16x32_f16(h01, W0[q][3], z, 0, 0, 0);
        z = __builtin_amdgcn_mfma_f32_16x16x32_f16(h02, W0[q][4], z, 0, 0, 0);
        z = __builtin_amdgcn_mfma_f32_16x16x32_f16(h03, W0[q][5], z, 0, 0, 0);
        accA[q] = z;
      }
#pragma unroll
      for (int r = 0; r < 4; ++r) {
        float cn = sigf(accA[1][r]) * c0[r] + sigf(accA[0][r]) * tanh_(accA[2][r]);
        c0[r] = cn;
        float hv = sigf(accA[3][r]) * tanh_(cn);
        h0t[p ^ 1][kb_w][lanep + r][jw] = (_Float16)hv;
      }
      if (j + 1 < T_STEPS) {  // stage x(j+1)
        int row = tid >> 5, kk = (tid & 31) << 1;
        const float* xp = x + (((long)(g * 16 + row)) * T_STEPS + (j + 1)) * 64 + kk;
        float2 v = *(const float2*)xp;
        h2v pxv; pxv.x = (_Float16)v.x; pxv.y = (_Float16)v.y;
        *(h2v*)&xt[p ^ 1][kk >> 5][(((kk >> 3) & 3) * 16) + row][kk & 7] = pxv;
      }
    }

    if (j >= 1) {
      // ---- B(j-1): layer 1 computes h1(j-1) ----
      h8v f10 = *(const h8v*)&h1t[p][0][l][0];
      h8v f11 = *(const h8v*)&h1t[p][1][l][0];
      h8v f12 = *(const h8v*)&h1t[p][2][l][0];
      h8v f13 = *(const h8v*)&h1t[p][3][l][0];
      f4v accB[4];
#pragma unroll
      for (int q = 0; q < 4; ++q) {
        const h8v* wb = &whh[((w * 4 + q) * 4) * 64 + l];
        h8v wh0 = wb[0];
        h8v wh1 = wb[64];
        h8v wh2 = wb[128];
        h8v wh3 = wb[192];
        f4v z = {bB[q], bB[q], bB[q], bB[q]};
        z = __builtin_amdgcn_mfma_f32_16x16x32_f16(h00, W1[q][0], z, 0, 0, 0);
        z = __builtin_amdgcn_mfma_f32_16x16x32_f16(h01, W1[q][1], z, 0, 0, 0);
        z = __builtin_amdgcn_mfma_f32_16x16x32_f16(h02, W1[q][2], z, 0, 0, 0);
        z = __builtin_amdgcn_mfma_f32_16x16x32_f16(h03, W1[q][3], z, 0, 0, 0);
        z = __builtin_amdgcn_mfma_f32_16x16x32_f16(f10, wh0, z, 0, 0, 0);
        z = __builtin_amdgcn_mfma_f32_16x16x32_f16(f11, wh1, z, 0, 0, 0);
        z = __builtin_amdgcn_mfma_f32_16x16x32_f16(f12, wh2, z, 0, 0, 0);
        z = __builtin_amdgcn_mfma_f32_16x16x32_f16(f13, wh3, z, 0, 0, 0);
        accB[q] = z;
      }
#pragma unroll
      for (int r = 0; r < 4; ++r) {
        float cn = sigf(accB[1][r]) * c1[r] + sigf(accB[0][r]) * tanh_(accB[2][r]);
        c1[r] = cn;
        float hv = sigf(accB[3][r]) * tanh_(cn);
        h1t[p ^ 1][kb_w][lanep + r][jw] = (_Float16)hv;
      }
    }
    __syncthreads();
  }

  // ---- output projection: y = h1(T-1) . Wout^T + bout ; h1(T-1) in h1t[1] ----
  if (tid < 16) {
    float acc = bout[0];
#pragma unroll 4
    for (int u = 0; u < 128; ++u) {
      float hval = (float)h1t[1][u >> 5][(((u >> 3) & 3) * 16) + tid][u & 7];
      acc = fmaf(hval, Wout[u], acc);
    }
    out[g * 16 + tid] = acc;
  }
}

}  // namespace

extern "C" void kernel_launch(void* const* d_in, const int* in_sizes, int n_in,
                              void* d_out, int out_size, void* d_ws, size_t ws_size,
                              hipStream_t stream) {
  const float* x    = (const float*)d_in[0];
  const float* Wih0 = (const float*)d_in[1];
  const float* Whh0 = (const float*)d_in[2];
  const float* b0   = (const float*)d_in[3];
  const float* Wih1 = (const float*)d_in[4];
  const float* Whh1 = (const float*)d_in[5];
  const float* b1   = (const float*)d_in[6];
  const float* Wout = (const float*)d_in[7];
  const float* bout = (const float*)d_in[8];
  float* out = (float*)d_out;

  char* ws = (char*)d_ws;
  _Float16* PA = (_Float16*)ws;             // 196608 B
  _Float16* PB = (_Float16*)(ws + 196608);  // 262144 B

  const int lds_bytes = 131072 + 8192 + 8192 + 4096;  // 151552
  hipFuncSetAttribute((const void*)lstm_block,
                      hipFuncAttributeMaxDynamicSharedMemorySize, lds_bytes);

  pack_w<<<dim3(896), dim3(256), 0, stream>>>(Wih0, Whh0, Wih1, Whh1, PA, PB);
  lstm_block<<<dim3(64), dim3(512), lds_bytes, stream>>>(
      x, PA, PB, b0, b1, Wout, bout, out);
}